// Round 14
// baseline (826.766 us; speedup 1.0000x reference)
//
#include <hip/hip_runtime.h>
#include <hip/hip_bf16.h>

#define BB 8
#define NN 1024
#define KK 20
#define EPSB 1e-5f

typedef __hip_bfloat16 bf16;
typedef __attribute__((ext_vector_type(8))) short sbf8;   // 8 bf16 = 4 VGPRs
typedef __attribute__((ext_vector_type(4))) float f32x4;

__device__ __forceinline__ float lrelu(float t){ return t >= 0.f ? t : 0.2f*t; }
__device__ __forceinline__ float ldin(const void* p, int i, int bf){
  return bf ? __bfloat162float(((const bf16*)p)[i]) : ((const float*)p)[i];
}
__device__ __forceinline__ unsigned short f2bf(float f){   // RNE fp32->bf16 bits
  unsigned u = __float_as_uint(f);
  return (unsigned short)((u + 0x7FFFu + ((u>>16)&1u)) >> 16);
}
__device__ __forceinline__ float bf2f(unsigned short us){
  return __uint_as_float((unsigned)us << 16);
}
__device__ __forceinline__ unsigned f2u_ord(float f){
  unsigned u = __float_as_uint(f);
  return (u & 0x80000000u) ? ~u : (u | 0x80000000u);
}
__device__ __forceinline__ float u2f_ord(unsigned u){
  return (u & 0x80000000u) ? __uint_as_float(u & 0x7fffffffu) : __uint_as_float(~u);
}
// inline dtype detect: full-wave ballot over x's first 64 words (fp32 N(0,1) data
// never has exp>=0xD0; packed-bf16 words mostly do).
__device__ __forceinline__ int detect_bf(const void* x){
  unsigned w = ((const unsigned*)x)[threadIdx.x & 63];
  unsigned e = (w >> 23) & 0xFFu;
  unsigned long long m = __ballot(e >= 0xD0u);
  return (__popcll(m) >= 32) ? 1 : 0;
}

// ---------------- conv0 stats: 32 blocks, 1 point/thread, shuffle-reduce + atomics
__global__ __launch_bounds__(256) void conv0_stats_kernel(
    const void* __restrict__ x,
    const void* __restrict__ w00, const void* __restrict__ w01,
    float* __restrict__ cstat){
  const int bf = detect_bf(x);
  int i = blockIdx.x*256 + threadIdx.x;
  int b = i >> 10, n = i & 1023;
  float wz[4], wy[4];
#pragma unroll
  for (int j=0;j<4;j++){ wz[j]=ldin(w00,j,bf); wy[j]=ldin(w01,j,bf); }
  float x0 = ldin(x,(b*3+0)*NN + n,bf);
  float x1 = ldin(x,(b*3+1)*NN + n,bf);
  float x2 = ldin(x,(b*3+2)*NN + n,bf);
  float vals[6];
  vals[0] = wz[0]*x0 + wz[1]*x1;  vals[1] = wz[2]*x0 + wz[3]*x1;   // z (w00, ch 0,1)
  vals[2] = wy[0]*x0 + wy[1]*x2;  vals[3] = wy[2]*x0 + wy[3]*x2;   // y (w01, ch 0,2)
  vals[4] = wy[0]*x1 + wy[1]*x2;  vals[5] = wy[2]*x1 + wy[3]*x2;   // u (w01, ch 1,2)
  int lane = threadIdx.x & 63;
#pragma unroll
  for (int j=0;j<6;j++){
    float s1 = vals[j], s2 = vals[j]*vals[j];
#pragma unroll
    for (int off=32; off; off>>=1){
      s1 += __shfl_xor(s1, off, 64);
      s2 += __shfl_xor(s2, off, 64);
    }
    if (lane == 0){
      atomicAdd(&cstat[2*j], s1);
      atomicAdd(&cstat[2*j+1], s2);
    }
  }
}

// ---------------- conv0 apply: BN+lrelu+gate, writes xc0 rows (16 floats, padded)
__global__ __launch_bounds__(256) void conv0_apply_kernel(
    const void* __restrict__ x,
    const void* __restrict__ w00, const void* __restrict__ g00, const void* __restrict__ b00,
    const void* __restrict__ w01, const void* __restrict__ g01, const void* __restrict__ b01,
    const float* __restrict__ cstat, float* __restrict__ xc0){
  const int bf = detect_bf(x);
  int i = blockIdx.x*256 + threadIdx.x;
  int b = i >> 10, n = i & 1023;
  float wz[4], wy[4];
#pragma unroll
  for (int j=0;j<4;j++){ wz[j]=ldin(w00,j,bf); wy[j]=ldin(w01,j,bf); }
  float sA[6], sC[6];
#pragma unroll
  for (int j=0;j<6;j++){
    float m = cstat[2*j] * (1.f/(BB*NN));
    float v = cstat[2*j+1] * (1.f/(BB*NN)) - m*m;
    float g, bv;
    if (j<2){ g=ldin(g00,j,bf); bv=ldin(b00,j,bf); }
    else if (j<4){ g=ldin(g01,j-2,bf); bv=ldin(b01,j-2,bf); }
    else { g=ldin(g01,j-4,bf); bv=ldin(b01,j-4,bf); }
    float a = g * rsqrtf(fmaxf(v,0.f) + EPSB);
    sA[j]=a; sC[j]=bv - m*a;
  }
  float x0 = ldin(x,(b*3+0)*NN + n,bf);
  float x1 = ldin(x,(b*3+1)*NN + n,bf);
  float x2 = ldin(x,(b*3+2)*NN + n,bf);
  float z0 = wz[0]*x0 + wz[1]*x1, z1 = wz[2]*x0 + wz[3]*x1;
  float y0 = wy[0]*x0 + wy[1]*x2, y1 = wy[2]*x0 + wy[3]*x2;
  float u0 = wy[0]*x1 + wy[1]*x2, u1 = wy[2]*x1 + wy[3]*x2;
  float* row = xc0 + (size_t)i*16;
  float4 r0, r1, r2, r3;
  r0.x=x0; r0.y=x1; r0.z=x2;
  r0.w=lrelu(sA[4]*u0+sC[4])*x0;
  r1.x=lrelu(sA[5]*u1+sC[5])*x0;
  r1.y=lrelu(sA[2]*y0+sC[2])*x1;
  r1.z=lrelu(sA[3]*y1+sC[3])*x1;
  r1.w=lrelu(sA[0]*z0+sC[0])*x2;
  r2.x=lrelu(sA[1]*z1+sC[1])*x2;
  r2.y=0.f; r2.z=0.f; r2.w=0.f;
  r3.x=0.f; r3.y=0.f; r3.z=0.f; r3.w=0.f;
  *(float4*)&row[0]  = r0;
  *(float4*)&row[4]  = r1;
  *(float4*)&row[8]  = r2;
  *(float4*)&row[12] = r3;
}

// ---------------- weight prep element
__device__ __forceinline__ void wuv_elem(const void* W, float* WdT, float* WcdT,
                                         int CIN, int COUT, int t, int bf){
  int c = t / COUT, o = t % COUT;
  if (c < CIN){
    float wd = ldin(W, o*(2*CIN)+c, bf);
    float wc = ldin(W, o*(2*CIN)+CIN+c, bf);
    WdT[t] = wd; WcdT[t] = wc - wd;
  } else {
    WdT[t] = 0.f; WcdT[t] = 0.f;
  }
}

// ---------------- fused prep: zero stats region + 4x wuv + wb5 pack (one launch)
#define NZERO (128+128+256+512+2048+8192+8192+16)
__global__ __launch_bounds__(256) void prep_kernel(
    const void* __restrict__ x,
    const void* __restrict__ w1, const void* __restrict__ w2,
    const void* __restrict__ w3, const void* __restrict__ w4,
    const void* __restrict__ w5,
    unsigned* __restrict__ zbase,
    float* __restrict__ w1d, float* __restrict__ w1c,
    float* __restrict__ w2d, float* __restrict__ w2c,
    float* __restrict__ w3d, float* __restrict__ w3c,
    float* __restrict__ w4d, float* __restrict__ w4c,
    unsigned short* __restrict__ wb5){
  const int bf = detect_bf(x);
  int t = blockIdx.x*256 + threadIdx.x;
  if (t < NZERO){ zbase[t] = 0u; return; }
  t -= NZERO;
  if (t < 768){ wuv_elem(w1, w1d, w1c, 9, 64, t, bf); return; }
  t -= 768;
  if (t < 4096){ wuv_elem(w2, w2d, w2c, 64, 64, t, bf); return; }
  t -= 4096;
  if (t < 8192){ wuv_elem(w3, w3d, w3c, 64, 128, t, bf); return; }
  t -= 8192;
  if (t < 32768){ wuv_elem(w4, w4d, w4c, 128, 256, t, bf); return; }
  t -= 32768;
  if (t < 1024*512) wb5[t] = f2bf(ldin(w5, t, bf));
}

// ---------------- fused negdist (on-the-fly row norms): 128x128 tiles, 8x8 acc.
// KCH=32 -> 33 KB LDS -> 4 blocks/CU (was 65 KB -> 2/CU, LDS-latency-bound at
// 2 waves/SIMD). Chunk order preserves per-thread c-summation order (bit-identical).
__global__ __launch_bounds__(256, 4) void knndist_kernel(
    const float* __restrict__ src, int ld, int coff, int CR,
    float* __restrict__ negD){
  extern __shared__ float lds[];
  const int KCH = (CR >= 32) ? 32 : 16;     // CR=12 -> 16 (xc0 cols 9..15 are zero)
  const int NG  = KCH >> 2;                 // 16B groups per row
  const int GM  = NG - 1;
  float* At = lds;
  float* Bt = lds + 128*KCH;
  float* xn = Bt + 128*KCH;
  int b = blockIdx.z, i0 = blockIdx.y*128, j0 = blockIdx.x*128;
  int tid = threadIdx.x;
  int ti = tid >> 4, tj = tid & 15;
  int gsa = ti & GM, gsb = tj & GM;
  float acc[8][8];
#pragma unroll
  for (int u=0;u<8;u++)
#pragma unroll
    for (int v=0;v<8;v++) acc[u][v]=0.f;
  float mynorm = 0.f;
  int nch = (CR + KCH - 1)/KCH;             // 1 (CR=12) / 2 (CR=64) / 4 (CR=128)
  for (int ch=0; ch<nch; ch++){
    int c0 = ch*KCH;
    __syncthreads();
    for (int t = tid; t < 2*128*NG; t += 256){
      int half = (t >= 128*NG);
      int tt = half ? t - 128*NG : t;
      int r = tt / NG, g = tt % NG;
      int base = half ? j0 : i0;
      float4 f = *(const float4*)&src[(size_t)(b*NN + base + r)*ld + coff + c0 + g*4];
      int gs = g ^ ((r>>3) & GM);
      float* dst = (half ? Bt : At) + r*KCH + gs*4;
      *(float4*)dst = f;
    }
    __syncthreads();
    {
      int r = tid & 127;
      const float* rowp = ((tid < 128) ? At : Bt) + r*KCH;
      float s = 0.f;
      for (int g=0; g<NG; g++){
        float4 f = *(const float4*)&rowp[g*4];
        s += f.x*f.x + f.y*f.y + f.z*f.z + f.w*f.w;
      }
      mynorm += s;
    }
    for (int g=0; g<NG; g++){
      float4 av[8];
#pragma unroll
      for (int u=0;u<8;u++)
        av[u] = *(const float4*)&At[(ti*8+u)*KCH + ((g ^ gsa)<<2)];
#pragma unroll
      for (int v=0;v<8;v++){
        float4 bv = *(const float4*)&Bt[(tj*8+v)*KCH + ((g ^ gsb)<<2)];
#pragma unroll
        for (int u=0;u<8;u++)
          acc[u][v] += av[u].x*bv.x + av[u].y*bv.y + av[u].z*bv.z + av[u].w*bv.w;
      }
    }
  }
  __syncthreads();
  xn[(tid < 128 ? 0 : 128) + (tid & 127)] = mynorm;
  __syncthreads();
  float xi[8], xj[8];
#pragma unroll
  for (int u=0;u<8;u++){ xi[u] = xn[ti*8+u]; xj[u] = xn[128 + tj*8+u]; }
#pragma unroll
  for (int u=0;u<8;u++){
    float* orow = &negD[((size_t)(b*NN + i0 + ti*8 + u))*NN + j0 + tj*8];
#pragma unroll
    for (int vg=0; vg<2; vg++){
      float4 ov;
      ov.x = 2.f*acc[u][vg*4+0] - xi[u] - xj[vg*4+0];
      ov.y = 2.f*acc[u][vg*4+1] - xi[u] - xj[vg*4+1];
      ov.z = 2.f*acc[u][vg*4+2] - xi[u] - xj[vg*4+2];
      ov.w = 2.f*acc[u][vg*4+3] - xi[u] - xj[vg*4+3];
      *(float4*)&orow[vg*4] = ov;
    }
  }
}

// ---------------- top-20: one wave per row; registers + 64-lane butterfly argmax
__global__ __launch_bounds__(256, 4) void topk_kernel(const float* __restrict__ negD,
                                                      int* __restrict__ idx){
  int row_id = (blockIdx.x*256 + threadIdx.x) >> 6;
  int lane = threadIdx.x & 63;
  if (row_id >= BB*NN) return;
  const float* row = negD + (size_t)row_id*NN;
  float v[16];
#pragma unroll
  for (int j=0;j<4;j++){
    float4 f = *(const float4*)&row[j*256 + lane*4];
    v[j*4+0]=f.x; v[j*4+1]=f.y; v[j*4+2]=f.z; v[j*4+3]=f.w;
  }
  int* orow = idx + (size_t)row_id*KK;
  for (int k=0;k<KK;k++){
    float bv = v[0]; int bs = 0;
#pragma unroll
    for (int s=1;s<16;s++){ if (v[s] > bv){ bv = v[s]; bs = s; } }
    int bidx = (bs>>2)*256 + lane*4 + (bs&3);
    unsigned long long key = ((unsigned long long)f2u_ord(bv) << 32) | (unsigned)(1023 - bidx);
#pragma unroll
    for (int off=32; off; off>>=1){
      unsigned long long o = __shfl_xor(key, off, 64);
      if (o > key) key = o;
    }
    int widx = 1023 - (int)(key & 0xFFFFFFFFu);
    if (lane == 0) orow[k] = widx;
    bool mine = (((widx >> 2) & 63) == lane);
    int wslot = ((widx >> 8) << 2) | (widx & 3);
#pragma unroll
    for (int s=0;s<16;s++){
      if (mine && s == wslot) v[s] = -1e30f;
    }
  }
}

// ---------------- u/v GEMM (after topk; u/v overlay dead negD region). PT=8 -> 1024 blocks.
template<int CINP,int COUT>
__global__ __launch_bounds__(256, 4) void uvgemm_kernel(
    const float* __restrict__ srcT, int ld, int coff,
    const float* __restrict__ WdT, const float* __restrict__ WcdT,
    float* __restrict__ ut, float* __restrict__ vt){
  constexpr int PT=8, G = 256/COUT, NP = (PT*COUT)/256;
  __shared__ float xs[PT*CINP];
  int tid = threadIdx.x;
  int base = blockIdx.x*PT;
  for (int t=tid; t<PT*CINP; t+=256){
    int p = t / CINP, c = t % CINP;
    xs[t] = srcT[(size_t)(base+p)*ld + coff + c];
  }
  __syncthreads();
  int o = tid % COUT, grp = tid / COUT;
  float u[NP], v[NP];
#pragma unroll
  for (int pp=0;pp<NP;pp++){ u[pp]=0.f; v[pp]=0.f; }
  for (int c=0;c<CINP;c+=4){
    float wd0 = WdT[(c+0)*COUT+o], wc0 = WcdT[(c+0)*COUT+o];
    float wd1 = WdT[(c+1)*COUT+o], wc1 = WcdT[(c+1)*COUT+o];
    float wd2 = WdT[(c+2)*COUT+o], wc2 = WcdT[(c+2)*COUT+o];
    float wd3 = WdT[(c+3)*COUT+o], wc3 = WcdT[(c+3)*COUT+o];
#pragma unroll
    for (int pp=0;pp<NP;pp++){
      float4 xv = *(const float4*)&xs[(grp+pp*G)*CINP + c];
      u[pp] = fmaf(xv.x,wd0,fmaf(xv.y,wd1,fmaf(xv.z,wd2,fmaf(xv.w,wd3,u[pp]))));
      v[pp] = fmaf(xv.x,wc0,fmaf(xv.y,wc1,fmaf(xv.z,wc2,fmaf(xv.w,wc3,v[pp]))));
    }
  }
#pragma unroll
  for (int pp=0;pp<NP;pp++){
    int p = grp + pp*G;
    ut[(size_t)(base+p)*COUT + o] = u[pp];
    vt[(size_t)(base+p)*COUT + o] = v[pp];
  }
}

// ---------------- gather: h[n,k,o] = ut[m(n,k)][o] + vt[n][o]; max/min + BN sums
template<int COUT>
__global__ __launch_bounds__(256, 4) void ebgather_kernel(
    const int* __restrict__ idx, const float* __restrict__ ut, const float* __restrict__ vt,
    float* __restrict__ hmaxb, float* __restrict__ hminb, float* __restrict__ stats){
  constexpr int CHG = COUT/64;
  __shared__ float sred[128];
  int w = threadIdx.x >> 6, lane = threadIdx.x & 63;
  int pb  = blockIdx.x / CHG;
  int chg = blockIdx.x % CHG;
  int n = pb*4 + w;
  int b = n >> 10;
  if (threadIdx.x < 128) sred[threadIdx.x] = 0.f;
  __syncthreads();
  const int* irow = idx + (size_t)n*KK;
  int m[KK];
#pragma unroll
  for (int k=0;k<KK;k++) m[k] = irow[k];
  int co = chg*64 + lane;
  float vr = vt[(size_t)n*COUT + co];
  float h[KK];
#pragma unroll
  for (int k=0;k<KK;k++)
    h[k] = ut[(size_t)(b*NN + m[k])*COUT + co] + vr;
  float hx=-1e30f, hn=1e30f, s1=0.f, s2=0.f;
#pragma unroll
  for (int k=0;k<KK;k++){
    hx = fmaxf(hx, h[k]);
    hn = fminf(hn, h[k]);
    s1 += h[k];
    s2 = fmaf(h[k], h[k], s2);
  }
  hmaxb[(size_t)n*COUT + co] = hx;
  hminb[(size_t)n*COUT + co] = hn;
  atomicAdd(&sred[lane], s1);
  atomicAdd(&sred[64+lane], s2);
  __syncthreads();
  if (threadIdx.x < 128){
    int which = threadIdx.x >> 6, l = threadIdx.x & 63;
    atomicAdd(&stats[which*COUT + chg*64 + l], sred[which*64 + l]);
  }
}

// ---------------- apply (finalize inline): out = lrelu(a*(a>=0?hmax:hmin)+c)
template<int COUT>
__global__ __launch_bounds__(256) void ebapply_kernel(
    const void* __restrict__ x,
    const float* __restrict__ hmaxb, const float* __restrict__ hminb,
    const float* __restrict__ stats, const void* __restrict__ g, const void* __restrict__ bb,
    float* __restrict__ outp, int outoff){
  const int bf = detect_bf(x);
  int t = blockIdx.x*256 + threadIdx.x;
  if (t >= BB*NN*COUT) return;
  int n = t / COUT, o = t % COUT;
  const float inv_count = 1.f/(BB*NN*KK);
  float m = stats[o]*inv_count;
  float var = stats[COUT+o]*inv_count - m*m;
  float a = ldin(g,o,bf)*rsqrtf(fmaxf(var,0.f) + EPSB);
  float c = ldin(bb,o,bf) - m*a;
  float h = (a >= 0.f) ? hmaxb[t] : hminb[t];
  outp[(size_t)n*512 + outoff + o] = lrelu(fmaf(a,h,c));
}

// ---------------- conv5 via MFMA bf16: single pass, h -> bf16 hbuf + BN stats.
__global__ __launch_bounds__(256, 3) void fc5_mfma(
    const float* __restrict__ xcat, const unsigned short* __restrict__ wb5,
    float* __restrict__ st5, unsigned short* __restrict__ hbufb){
  __shared__ unsigned As[16*256];
  int tid = threadIdx.x;
  int pblk = blockIdx.x >> 2;
  int seg  = blockIdx.x & 3;
  int n0g = pblk*16;
  for (int t = tid; t < 16*256; t += 256){
    int r = t >> 8, d = t & 255;
    float2 xv = *(const float2*)&xcat[(size_t)(n0g + r)*512 + d*2];
    unsigned pk = (unsigned)f2bf(xv.x) | ((unsigned)f2bf(xv.y) << 16);
    int gs = (d >> 2) ^ r;
    As[r*256 + (gs<<2) + (d&3)] = pk;
  }
  __syncthreads();
  int w = tid>>6, lane = tid&63, col = lane&15, quad = lane>>4;
  sbf8 afr[16];
#pragma unroll
  for (int ks=0; ks<16; ks++){
    int gs = (ks*4 + quad) ^ col;
    afr[ks] = *(const sbf8*)((const unsigned short*)As + col*512 + gs*8);
  }
#pragma unroll 1
  for (int i=0;i<4;i++){
    int obase = seg*256 + w*64 + i*16;
    const unsigned short* wrow = wb5 + (size_t)(obase+col)*512 + quad*8;
    f32x4 a0 = {0.f,0.f,0.f,0.f}, a1 = {0.f,0.f,0.f,0.f};
    f32x4 a2 = {0.f,0.f,0.f,0.f}, a3 = {0.f,0.f,0.f,0.f};
#pragma unroll
    for (int ks=0; ks<4; ks++){
      sbf8 b0 = *(const sbf8*)(wrow + (ks*4+0)*32);
      sbf8 b1 = *(const sbf8*)(wrow + (ks*4+1)*32);
      sbf8 b2 = *(const sbf8*)(wrow + (ks*4+2)*32);
      sbf8 b3 = *(const sbf8*)(wrow + (ks*4+3)*32);
      a0 = __builtin_amdgcn_mfma_f32_16x16x32_bf16(afr[ks*4+0], b0, a0, 0, 0, 0);
      a1 = __builtin_amdgcn_mfma_f32_16x16x32_bf16(afr[ks*4+1], b1, a1, 0, 0, 0);
      a2 = __builtin_amdgcn_mfma_f32_16x16x32_bf16(afr[ks*4+2], b2, a2, 0, 0, 0);
      a3 = __builtin_amdgcn_mfma_f32_16x16x32_bf16(afr[ks*4+3], b3, a3, 0, 0, 0);
    }
    f32x4 acc = (a0 + a1) + (a2 + a3);
    float s1 = acc.x+acc.y+acc.z+acc.w;
    float s2 = acc.x*acc.x + acc.y*acc.y + acc.z*acc.z + acc.w*acc.w;
    s1 += __shfl_xor(s1,16,64); s2 += __shfl_xor(s2,16,64);
    s1 += __shfl_xor(s1,32,64); s2 += __shfl_xor(s2,32,64);
    if (lane < 16){
      atomicAdd(&st5[obase+lane], s1);
      atomicAdd(&st5[1024+obase+lane], s2);
    }
    unsigned short hv[4] = {f2bf(acc.x), f2bf(acc.y), f2bf(acc.z), f2bf(acc.w)};
#pragma unroll
    for (int r=0;r<4;r++)
      hbufb[(size_t)(n0g + quad*4 + r)*1024 + obase + col] = hv[r];
  }
}

// ---------------- pool over n (finalize inline): max & mean of lrelu(a*h+c); h bf16
__global__ __launch_bounds__(256) void pool5_kernel(
    const void* __restrict__ x,
    const unsigned short* __restrict__ hbufb, const float* __restrict__ st5,
    const void* __restrict__ g5, const void* __restrict__ b5,
    unsigned* __restrict__ pmax, float* __restrict__ psum){
  const int bf = detect_bf(x);
  int b = blockIdx.x >> 5;
  int ns = blockIdx.x & 31;
  int o4 = threadIdx.x*4;
  const float inv_count = 1.f/(BB*NN);
  float a[4], c[4];
#pragma unroll
  for (int j=0;j<4;j++){
    int o = o4+j;
    float m = st5[o]*inv_count;
    float var = st5[1024+o]*inv_count - m*m;
    a[j] = ldin(g5,o,bf)*rsqrtf(fmaxf(var,0.f)+EPSB);
    c[j] = ldin(b5,o,bf) - m*a[j];
  }
  float mx0=-1e30f,mx1=-1e30f,mx2=-1e30f,mx3=-1e30f;
  float sm0=0.f,sm1=0.f,sm2=0.f,sm3=0.f;
  for (int n = ns*32; n < ns*32+32; n++){
    ushort4 hu = *(const ushort4*)&hbufb[(size_t)(b*NN + n)*1024 + o4];
    float t0 = lrelu(fmaf(a[0],bf2f(hu.x),c[0]));
    float t1 = lrelu(fmaf(a[1],bf2f(hu.y),c[1]));
    float t2 = lrelu(fmaf(a[2],bf2f(hu.z),c[2]));
    float t3 = lrelu(fmaf(a[3],bf2f(hu.w),c[3]));
    mx0=fmaxf(mx0,t0); mx1=fmaxf(mx1,t1); mx2=fmaxf(mx2,t2); mx3=fmaxf(mx3,t3);
    sm0+=t0; sm1+=t1; sm2+=t2; sm3+=t3;
  }
  atomicMax(&pmax[b*1024+o4+0], f2u_ord(mx0));
  atomicMax(&pmax[b*1024+o4+1], f2u_ord(mx1));
  atomicMax(&pmax[b*1024+o4+2], f2u_ord(mx2));
  atomicMax(&pmax[b*1024+o4+3], f2u_ord(mx3));
  atomicAdd(&psum[b*1024+o4+0], sm0);
  atomicAdd(&psum[b*1024+o4+1], sm1);
  atomicAdd(&psum[b*1024+o4+2], sm2);
  atomicAdd(&psum[b*1024+o4+3], sm3);
}

// ---------------- FC head (fc6 inlines pool_finalize from pmax/psum)
__global__ __launch_bounds__(256) void fc6_kernel(
    const void* __restrict__ x,
    const unsigned* __restrict__ pmax, const float* __restrict__ psum,
    const void* __restrict__ W,
    const void* __restrict__ g, const void* __restrict__ bb, float* __restrict__ y6){
  __shared__ float red[8][256];
  int o = blockIdx.x, tid = threadIdx.x;
  const int bf = detect_bf(x);
  float part[8];
#pragma unroll
  for (int b=0;b<8;b++) part[b]=0.f;
  for (int c=tid;c<2048;c+=256){
    float wv = ldin(W,o*2048+c,bf);
#pragma unroll
    for (int b=0;b<8;b++){
      float pv = (c < 1024) ? u2f_ord(pmax[b*1024+c])
                            : psum[b*1024 + (c-1024)] * (1.f/1024.f);
      part[b] = fmaf(pv, wv, part[b]);
    }
  }
#pragma unroll
  for (int b=0;b<8;b++) red[b][tid]=part[b];
  __syncthreads();
  for (int s=128;s;s>>=1){
    if (tid<s){
#pragma unroll
      for (int b=0;b<8;b++) red[b][tid]+=red[b][tid+s];
    }
    __syncthreads();
  }
  if (tid==0){
    float y[8], m=0.f;
#pragma unroll
    for (int b=0;b<8;b++){ y[b]=red[b][0]; m+=y[b]; }
    m *= 0.125f;
    float v=0.f;
#pragma unroll
    for (int b=0;b<8;b++){ float d=y[b]-m; v += d*d; }
    v *= 0.125f;
    float a=ldin(g,o,bf)*rsqrtf(fmaxf(v,0.f)+EPSB), c0=ldin(bb,o,bf)-m*a;
#pragma unroll
    for (int b=0;b<8;b++) y6[b*512+o]=lrelu(fmaf(a,y[b],c0));
  }
}

__global__ __launch_bounds__(256) void fc7_kernel(
    const void* __restrict__ x,
    const float* __restrict__ y6, const void* __restrict__ W, const void* __restrict__ bias,
    const void* __restrict__ g, const void* __restrict__ bb, float* __restrict__ y7){
  __shared__ float red[8][256];
  int o = blockIdx.x, tid = threadIdx.x;
  const int bf = detect_bf(x);
  float part[8];
#pragma unroll
  for (int b=0;b<8;b++) part[b]=0.f;
  for (int c=tid;c<512;c+=256){
    float wv = ldin(W,o*512+c,bf);
#pragma unroll
    for (int b=0;b<8;b++) part[b] = fmaf(y6[b*512+c], wv, part[b]);
  }
#pragma unroll
  for (int b=0;b<8;b++) red[b][tid]=part[b];
  __syncthreads();
  for (int s=128;s;s>>=1){
    if (tid<s){
#pragma unroll
      for (int b=0;b<8;b++) red[b][tid]+=red[b][tid+s];
    }
    __syncthreads();
  }
  if (tid==0){
    float bs = ldin(bias,o,bf);
    float y[8], m=0.f;
#pragma unroll
    for (int b=0;b<8;b++){ y[b]=red[b][0]+bs; m+=y[b]; }
    m *= 0.125f;
    float v=0.f;
#pragma unroll
    for (int b=0;b<8;b++){ float d=y[b]-m; v += d*d; }
    v *= 0.125f;
    float a=ldin(g,o,bf)*rsqrtf(fmaxf(v,0.f)+EPSB), c0=ldin(bb,o,bf)-m*a;
#pragma unroll
    for (int b=0;b<8;b++) y7[b*256+o]=lrelu(fmaf(a,y[b],c0));
  }
}

__global__ __launch_bounds__(256) void fc8_kernel(
    const void* __restrict__ x,
    const float* __restrict__ y7, const void* __restrict__ W, const void* __restrict__ bias,
    void* __restrict__ out){
  __shared__ float red[8][256];
  int o = blockIdx.x, tid = threadIdx.x;
  const int bf = detect_bf(x);
  float wv = ldin(W,o*256+tid,bf);
#pragma unroll
  for (int b=0;b<8;b++) red[b][tid] = y7[b*256+tid]*wv;
  __syncthreads();
  for (int s=128;s;s>>=1){
    if (tid<s){
#pragma unroll
      for (int b=0;b<8;b++) red[b][tid]+=red[b][tid+s];
    }
    __syncthreads();
  }
  if (tid==0){
    float bs = ldin(bias,o,bf);
#pragma unroll
    for (int b=0;b<8;b++){
      float r = red[b][0]+bs;
      if (bf) ((bf16*)out)[b*40+o] = __float2bfloat16(r);
      else    ((float*)out)[b*40+o] = r;
    }
  }
}

extern "C" void kernel_launch(void* const* d_in, const int* in_sizes, int n_in,
                              void* d_out, int out_size, void* d_ws, size_t ws_size,
                              hipStream_t stream){
  const void* x    = d_in[0];
  const void* w00  = d_in[1];
  const void* g00  = d_in[2];
  const void* b00  = d_in[3];
  const void* w01  = d_in[4];
  const void* g01  = d_in[5];
  const void* b01  = d_in[6];
  const void* w1   = d_in[7];  const void* g1 = d_in[8];  const void* b1 = d_in[9];
  const void* w2   = d_in[10]; const void* g2 = d_in[11]; const void* b2 = d_in[12];
  const void* w3   = d_in[13]; const void* g3 = d_in[14]; const void* b3 = d_in[15];
  const void* w4   = d_in[16]; const void* g4 = d_in[17]; const void* b4 = d_in[18];
  const void* w5   = d_in[19]; const void* g5 = d_in[20]; const void* b5 = d_in[21];
  const void* w6   = d_in[22]; const void* g6 = d_in[23]; const void* b6 = d_in[24];
  const void* w7   = d_in[25]; const void* bias7 = d_in[26];
  const void* g7   = d_in[27]; const void* b7 = d_in[28];
  const void* w8   = d_in[29]; const void* bias8 = d_in[30];

  float* ws = (float*)d_ws;
  // workspace layout (float offsets)
  size_t o_xc0  = 0;                              // B*N*16
  size_t o_xcat = o_xc0  + (size_t)BB*NN*16;      // B*N*512
  size_t o_negd = o_xcat + (size_t)BB*NN*512;     // B*N*N (u/v/hmax/hmin after topk; h5)
  size_t o_xx   = o_negd + (size_t)BB*NN*NN;      // B*N (unused)
  size_t o_w1d  = o_xx   + (size_t)BB*NN;         // 12*64
  size_t o_w1c  = o_w1d  + 12*64;
  size_t o_w2d  = o_w1c  + 12*64;                 // 64*64
  size_t o_w2c  = o_w2d  + 64*64;
  size_t o_w3d  = o_w2c  + 64*64;                 // 64*128
  size_t o_w3c  = o_w3d  + 64*128;
  size_t o_w4d  = o_w3c  + 64*128;                // 128*256
  size_t o_w4c  = o_w4d  + 128*256;
  size_t o_wb5  = o_w4c  + 128*256;               // 1024*512 bf16 = 262144 floats
  size_t o_st1  = o_wb5  + 262144;                // 128  (zero region starts here)
  size_t o_st2  = o_st1  + 128;                   // 128
  size_t o_st3  = o_st2  + 128;                   // 256
  size_t o_st4  = o_st3  + 256;                   // 512
  size_t o_st5  = o_st4  + 512;                   // 2048
  size_t o_pmax = o_st5  + 2048;                  // 8*1024 (uint)
  size_t o_psum = o_pmax + 8192;                  // 8*1024
  size_t o_cst  = o_psum + 8192;                  // 16 (conv0 stats; zero region ends)
  size_t o_idx  = o_cst  + 16;                    // B*N*20 ints
  size_t o_y6   = o_idx  + (size_t)BB*NN*KK;      // 8*512
  size_t o_y7   = o_y6   + 4096;                  // 8*256

  // overlays on the negD region (written only AFTER topk consumed negD):
  size_t o_u    = o_negd;
  size_t o_v    = o_negd + (size_t)BB*NN*256;
  size_t o_hmax = o_negd + (size_t)2*BB*NN*256;
  size_t o_hmin = o_negd + (size_t)3*BB*NN*256;
  size_t o_h5   = o_negd;                         // B*N*1024 bf16 (after eb4 apply)

  int* idxp = (int*)(ws + o_idx);
  float* negD = ws + o_negd;
  float* xc0  = ws + o_xc0;
  float* xcat = ws + o_xcat;
  float* up   = ws + o_u;
  float* vp   = ws + o_v;
  float* hxp  = ws + o_hmax;
  float* hnp  = ws + o_hmin;
  unsigned short* wb5 = (unsigned short*)(ws + o_wb5);
  unsigned short* h5b = (unsigned short*)(ws + o_h5);

  // fused prep: zero (NZERO u32 at o_st1) + weight transforms + wb5 pack
  const int PREP_TOTAL = NZERO + 768 + 4096 + 8192 + 32768 + 1024*512;
  prep_kernel<<<(PREP_TOTAL+255)/256,256,0,stream>>>(
      x, w1,w2,w3,w4,w5, (unsigned*)(ws + o_st1),
      ws+o_w1d, ws+o_w1c, ws+o_w2d, ws+o_w2c,
      ws+o_w3d, ws+o_w3c, ws+o_w4d, ws+o_w4c, wb5);

  conv0_stats_kernel<<<32,256,0,stream>>>(x, w00, w01, ws+o_cst);
  conv0_apply_kernel<<<32,256,0,stream>>>(x, w00,g00,b00, w01,g01,b01, ws+o_cst, xc0);

  dim3 kgrid(NN/128, NN/128, BB);               // 512 blocks
  const size_t KLDS16 = (2*128*16 + 256)*4;     // CR=12 (KCH=16): ~17 KB
  const size_t KLDS32 = (2*128*32 + 256)*4;     // CR=64/128 (KCH=32): ~33 KB -> 4/CU
  const int UVG = BB*NN/8;                      // 1024 blocks (PT=8)

  // ---- edge block 1
  knndist_kernel<<<kgrid,256, KLDS16, stream>>>(xc0, 16, 0, 12, negD);
  topk_kernel<<<BB*NN/4,256,0,stream>>>(negD, idxp);
  uvgemm_kernel<12,64><<<UVG,256,0,stream>>>(xc0, 16, 0, ws+o_w1d, ws+o_w1c, up, vp);
  ebgather_kernel<64><<<(BB*NN/4)*1,256,0,stream>>>(idxp, up, vp, hxp, hnp, ws+o_st1);
  ebapply_kernel<64><<<BB*NN*64/256,256,0,stream>>>(x, hxp, hnp, ws+o_st1, g1, b1, xcat, 0);

  // ---- edge block 2
  knndist_kernel<<<kgrid,256, KLDS32, stream>>>(xcat, 512, 0, 64, negD);
  topk_kernel<<<BB*NN/4,256,0,stream>>>(negD, idxp);
  uvgemm_kernel<64,64><<<UVG,256,0,stream>>>(xcat, 512, 0, ws+o_w2d, ws+o_w2c, up, vp);
  ebgather_kernel<64><<<(BB*NN/4)*1,256,0,stream>>>(idxp, up, vp, hxp, hnp, ws+o_st2);
  ebapply_kernel<64><<<BB*NN*64/256,256,0,stream>>>(x, hxp, hnp, ws+o_st2, g2, b2, xcat, 64);

  // ---- edge block 3
  knndist_kernel<<<kgrid,256, KLDS32, stream>>>(xcat, 512, 64, 64, negD);
  topk_kernel<<<BB*NN/4,256,0,stream>>>(negD, idxp);
  uvgemm_kernel<64,128><<<UVG,256,0,stream>>>(xcat, 512, 64, ws+o_w3d, ws+o_w3c, up, vp);
  ebgather_kernel<128><<<(BB*NN/4)*2,256,0,stream>>>(idxp, up, vp, hxp, hnp, ws+o_st3);
  ebapply_kernel<128><<<BB*NN*128/256,256,0,stream>>>(x, hxp, hnp, ws+o_st3, g3, b3, xcat, 128);

  // ---- edge block 4
  knndist_kernel<<<kgrid,256, KLDS32, stream>>>(xcat, 512, 128, 128, negD);
  topk_kernel<<<BB*NN/4,256,0,stream>>>(negD, idxp);
  uvgemm_kernel<128,256><<<UVG,256,0,stream>>>(xcat, 512, 128, ws+o_w4d, ws+o_w4c, up, vp);
  ebgather_kernel<256><<<(BB*NN/4)*4,256,0,stream>>>(idxp, up, vp, hxp, hnp, ws+o_st4);
  ebapply_kernel<256><<<BB*NN*256/256,256,0,stream>>>(x, hxp, hnp, ws+o_st4, g4, b4, xcat, 256);

  // ---- conv5 MFMA + pool
  fc5_mfma<<<(BB*NN/16)*4,256,0,stream>>>(xcat, wb5, ws+o_st5, h5b);
  pool5_kernel<<<BB*32,256,0,stream>>>(x, h5b, ws+o_st5, g5, b5,
                                       (unsigned*)(ws+o_pmax), ws+o_psum);

  // ---- FC head (fc6 reads pmax/psum directly)
  fc6_kernel<<<512,256,0,stream>>>(x, (unsigned*)(ws+o_pmax), ws+o_psum, w6, g6, b6, ws+o_y6);
  fc7_kernel<<<256,256,0,stream>>>(x, ws+o_y6, w7, bias7, g7, b7, ws+o_y7);
  fc8_kernel<<<40,256,0,stream>>>(x, ws+o_y7, w8, bias8, d_out);
}

// Round 15
// 794.303 us; speedup vs baseline: 1.0409x; 1.0409x over previous
//
#include <hip/hip_runtime.h>
#include <hip/hip_bf16.h>

#define BB 8
#define NN 1024
#define KK 20
#define EPSB 1e-5f

typedef __hip_bfloat16 bf16;
typedef __attribute__((ext_vector_type(8))) short sbf8;   // 8 bf16 = 4 VGPRs
typedef __attribute__((ext_vector_type(4))) float f32x4;

__device__ __forceinline__ float lrelu(float t){ return t >= 0.f ? t : 0.2f*t; }
__device__ __forceinline__ float ldin(const void* p, int i, int bf){
  return bf ? __bfloat162float(((const bf16*)p)[i]) : ((const float*)p)[i];
}
__device__ __forceinline__ unsigned short f2bf(float f){   // RNE fp32->bf16 bits
  unsigned u = __float_as_uint(f);
  return (unsigned short)((u + 0x7FFFu + ((u>>16)&1u)) >> 16);
}
__device__ __forceinline__ float bf2f(unsigned short us){
  return __uint_as_float((unsigned)us << 16);
}
__device__ __forceinline__ unsigned f2u_ord(float f){
  unsigned u = __float_as_uint(f);
  return (u & 0x80000000u) ? ~u : (u | 0x80000000u);
}
__device__ __forceinline__ float u2f_ord(unsigned u){
  return (u & 0x80000000u) ? __uint_as_float(u & 0x7fffffffu) : __uint_as_float(~u);
}
// inline dtype detect: full-wave ballot over x's first 64 words (fp32 N(0,1) data
// never has exp>=0xD0; packed-bf16 words mostly do).
__device__ __forceinline__ int detect_bf(const void* x){
  unsigned w = ((const unsigned*)x)[threadIdx.x & 63];
  unsigned e = (w >> 23) & 0xFFu;
  unsigned long long m = __ballot(e >= 0xD0u);
  return (__popcll(m) >= 32) ? 1 : 0;
}

// ---------------- conv0 stats: 32 blocks, 1 point/thread, shuffle-reduce + atomics
__global__ __launch_bounds__(256) void conv0_stats_kernel(
    const void* __restrict__ x,
    const void* __restrict__ w00, const void* __restrict__ w01,
    float* __restrict__ cstat){
  const int bf = detect_bf(x);
  int i = blockIdx.x*256 + threadIdx.x;
  int b = i >> 10, n = i & 1023;
  float wz[4], wy[4];
#pragma unroll
  for (int j=0;j<4;j++){ wz[j]=ldin(w00,j,bf); wy[j]=ldin(w01,j,bf); }
  float x0 = ldin(x,(b*3+0)*NN + n,bf);
  float x1 = ldin(x,(b*3+1)*NN + n,bf);
  float x2 = ldin(x,(b*3+2)*NN + n,bf);
  float vals[6];
  vals[0] = wz[0]*x0 + wz[1]*x1;  vals[1] = wz[2]*x0 + wz[3]*x1;   // z (w00, ch 0,1)
  vals[2] = wy[0]*x0 + wy[1]*x2;  vals[3] = wy[2]*x0 + wy[3]*x2;   // y (w01, ch 0,2)
  vals[4] = wy[0]*x1 + wy[1]*x2;  vals[5] = wy[2]*x1 + wy[3]*x2;   // u (w01, ch 1,2)
  int lane = threadIdx.x & 63;
#pragma unroll
  for (int j=0;j<6;j++){
    float s1 = vals[j], s2 = vals[j]*vals[j];
#pragma unroll
    for (int off=32; off; off>>=1){
      s1 += __shfl_xor(s1, off, 64);
      s2 += __shfl_xor(s2, off, 64);
    }
    if (lane == 0){
      atomicAdd(&cstat[2*j], s1);
      atomicAdd(&cstat[2*j+1], s2);
    }
  }
}

// ---------------- conv0 apply: BN+lrelu+gate, writes xc0 rows (16 floats, padded)
__global__ __launch_bounds__(256) void conv0_apply_kernel(
    const void* __restrict__ x,
    const void* __restrict__ w00, const void* __restrict__ g00, const void* __restrict__ b00,
    const void* __restrict__ w01, const void* __restrict__ g01, const void* __restrict__ b01,
    const float* __restrict__ cstat, float* __restrict__ xc0){
  const int bf = detect_bf(x);
  int i = blockIdx.x*256 + threadIdx.x;
  int b = i >> 10, n = i & 1023;
  float wz[4], wy[4];
#pragma unroll
  for (int j=0;j<4;j++){ wz[j]=ldin(w00,j,bf); wy[j]=ldin(w01,j,bf); }
  float sA[6], sC[6];
#pragma unroll
  for (int j=0;j<6;j++){
    float m = cstat[2*j] * (1.f/(BB*NN));
    float v = cstat[2*j+1] * (1.f/(BB*NN)) - m*m;
    float g, bv;
    if (j<2){ g=ldin(g00,j,bf); bv=ldin(b00,j,bf); }
    else if (j<4){ g=ldin(g01,j-2,bf); bv=ldin(b01,j-2,bf); }
    else { g=ldin(g01,j-4,bf); bv=ldin(b01,j-4,bf); }
    float a = g * rsqrtf(fmaxf(v,0.f) + EPSB);
    sA[j]=a; sC[j]=bv - m*a;
  }
  float x0 = ldin(x,(b*3+0)*NN + n,bf);
  float x1 = ldin(x,(b*3+1)*NN + n,bf);
  float x2 = ldin(x,(b*3+2)*NN + n,bf);
  float z0 = wz[0]*x0 + wz[1]*x1, z1 = wz[2]*x0 + wz[3]*x1;
  float y0 = wy[0]*x0 + wy[1]*x2, y1 = wy[2]*x0 + wy[3]*x2;
  float u0 = wy[0]*x1 + wy[1]*x2, u1 = wy[2]*x1 + wy[3]*x2;
  float* row = xc0 + (size_t)i*16;
  float4 r0, r1, r2, r3;
  r0.x=x0; r0.y=x1; r0.z=x2;
  r0.w=lrelu(sA[4]*u0+sC[4])*x0;
  r1.x=lrelu(sA[5]*u1+sC[5])*x0;
  r1.y=lrelu(sA[2]*y0+sC[2])*x1;
  r1.z=lrelu(sA[3]*y1+sC[3])*x1;
  r1.w=lrelu(sA[0]*z0+sC[0])*x2;
  r2.x=lrelu(sA[1]*z1+sC[1])*x2;
  r2.y=0.f; r2.z=0.f; r2.w=0.f;
  r3.x=0.f; r3.y=0.f; r3.z=0.f; r3.w=0.f;
  *(float4*)&row[0]  = r0;
  *(float4*)&row[4]  = r1;
  *(float4*)&row[8]  = r2;
  *(float4*)&row[12] = r3;
}

// ---------------- weight prep element
__device__ __forceinline__ void wuv_elem(const void* W, float* WdT, float* WcdT,
                                         int CIN, int COUT, int t, int bf){
  int c = t / COUT, o = t % COUT;
  if (c < CIN){
    float wd = ldin(W, o*(2*CIN)+c, bf);
    float wc = ldin(W, o*(2*CIN)+CIN+c, bf);
    WdT[t] = wd; WcdT[t] = wc - wd;
  } else {
    WdT[t] = 0.f; WcdT[t] = 0.f;
  }
}

// ---------------- fused prep: zero stats region + 4x wuv + wb5 pack (one launch)
#define NZERO (128+128+256+512+2048+8192+8192+16)
__global__ __launch_bounds__(256) void prep_kernel(
    const void* __restrict__ x,
    const void* __restrict__ w1, const void* __restrict__ w2,
    const void* __restrict__ w3, const void* __restrict__ w4,
    const void* __restrict__ w5,
    unsigned* __restrict__ zbase,
    float* __restrict__ w1d, float* __restrict__ w1c,
    float* __restrict__ w2d, float* __restrict__ w2c,
    float* __restrict__ w3d, float* __restrict__ w3c,
    float* __restrict__ w4d, float* __restrict__ w4c,
    unsigned short* __restrict__ wb5){
  const int bf = detect_bf(x);
  int t = blockIdx.x*256 + threadIdx.x;
  if (t < NZERO){ zbase[t] = 0u; return; }
  t -= NZERO;
  if (t < 768){ wuv_elem(w1, w1d, w1c, 9, 64, t, bf); return; }
  t -= 768;
  if (t < 4096){ wuv_elem(w2, w2d, w2c, 64, 64, t, bf); return; }
  t -= 4096;
  if (t < 8192){ wuv_elem(w3, w3d, w3c, 64, 128, t, bf); return; }
  t -= 8192;
  if (t < 32768){ wuv_elem(w4, w4d, w4c, 128, 256, t, bf); return; }
  t -= 32768;
  if (t < 1024*512) wb5[t] = f2bf(ldin(w5, t, bf));
}

// ---------------- fused negdist (on-the-fly row norms): 128x128 tiles, 8x8 acc.
// KCH=64 (r11/r13-best config; KCH=32 regressed — barrier-bound, r14).
__global__ __launch_bounds__(256, 2) void knndist_kernel(
    const float* __restrict__ src, int ld, int coff, int CR,
    float* __restrict__ negD){
  extern __shared__ float lds[];
  const int KCH = (CR >= 64) ? 64 : 16;     // CR=12 -> 16 (xc0 cols 9..15 are zero)
  const int NG  = KCH >> 2;
  const int GM  = NG - 1;
  float* At = lds;
  float* Bt = lds + 128*KCH;
  float* xn = Bt + 128*KCH;
  int b = blockIdx.z, i0 = blockIdx.y*128, j0 = blockIdx.x*128;
  int tid = threadIdx.x;
  int ti = tid >> 4, tj = tid & 15;
  int gsa = ti & GM, gsb = tj & GM;
  float acc[8][8];
#pragma unroll
  for (int u=0;u<8;u++)
#pragma unroll
    for (int v=0;v<8;v++) acc[u][v]=0.f;
  float mynorm = 0.f;
  int nch = (CR + KCH - 1)/KCH;
  for (int ch=0; ch<nch; ch++){
    int c0 = ch*KCH;
    __syncthreads();
    for (int t = tid; t < 2*128*NG; t += 256){
      int half = (t >= 128*NG);
      int tt = half ? t - 128*NG : t;
      int r = tt / NG, g = tt % NG;
      int base = half ? j0 : i0;
      float4 f = *(const float4*)&src[(size_t)(b*NN + base + r)*ld + coff + c0 + g*4];
      int gs = g ^ ((r>>3) & GM);
      float* dst = (half ? Bt : At) + r*KCH + gs*4;
      *(float4*)dst = f;
    }
    __syncthreads();
    {
      int r = tid & 127;
      const float* rowp = ((tid < 128) ? At : Bt) + r*KCH;
      float s = 0.f;
      for (int g=0; g<NG; g++){
        float4 f = *(const float4*)&rowp[g*4];
        s += f.x*f.x + f.y*f.y + f.z*f.z + f.w*f.w;
      }
      mynorm += s;
    }
    for (int g=0; g<NG; g++){
      float4 av[8];
#pragma unroll
      for (int u=0;u<8;u++)
        av[u] = *(const float4*)&At[(ti*8+u)*KCH + ((g ^ gsa)<<2)];
#pragma unroll
      for (int v=0;v<8;v++){
        float4 bv = *(const float4*)&Bt[(tj*8+v)*KCH + ((g ^ gsb)<<2)];
#pragma unroll
        for (int u=0;u<8;u++)
          acc[u][v] += av[u].x*bv.x + av[u].y*bv.y + av[u].z*bv.z + av[u].w*bv.w;
      }
    }
  }
  __syncthreads();
  xn[(tid < 128 ? 0 : 128) + (tid & 127)] = mynorm;
  __syncthreads();
  float xi[8], xj[8];
#pragma unroll
  for (int u=0;u<8;u++){ xi[u] = xn[ti*8+u]; xj[u] = xn[128 + tj*8+u]; }
#pragma unroll
  for (int u=0;u<8;u++){
    float* orow = &negD[((size_t)(b*NN + i0 + ti*8 + u))*NN + j0 + tj*8];
#pragma unroll
    for (int vg=0; vg<2; vg++){
      float4 ov;
      ov.x = 2.f*acc[u][vg*4+0] - xi[u] - xj[vg*4+0];
      ov.y = 2.f*acc[u][vg*4+1] - xi[u] - xj[vg*4+1];
      ov.z = 2.f*acc[u][vg*4+2] - xi[u] - xj[vg*4+2];
      ov.w = 2.f*acc[u][vg*4+3] - xi[u] - xj[vg*4+3];
      *(float4*)&orow[vg*4] = ov;
    }
  }
}

// ---------------- fused top-20 + u/v GEMM (independent work, disjoint block ranges;
// u/v live in a DEDICATED region — not overlaying negD — so no r12-style race).
// blocks [0, 2048): topk, one wave per row.  blocks [2048, 2048+512): uvgemm PT=16.
template<int CINP,int COUT>
__global__ __launch_bounds__(256, 4) void topkuv_kernel(
    const float* __restrict__ negD, int* __restrict__ idx,
    const float* __restrict__ srcT, int ld, int coff,
    const float* __restrict__ WdT, const float* __restrict__ WcdT,
    float* __restrict__ ut, float* __restrict__ vt){
  __shared__ float xs[16*CINP];
  int tid = threadIdx.x;
  if (blockIdx.x >= 2048){
    // ---------- uvgemm
    constexpr int PT=16, G = 256/COUT, NP = PT/G;
    int base = (blockIdx.x - 2048)*PT;
    for (int t=tid; t<PT*CINP; t+=256){
      int p = t / CINP, c = t % CINP;
      xs[t] = srcT[(size_t)(base+p)*ld + coff + c];
    }
    __syncthreads();
    int o = tid % COUT, grp = tid / COUT;
    float u[NP], v[NP];
#pragma unroll
    for (int pp=0;pp<NP;pp++){ u[pp]=0.f; v[pp]=0.f; }
    for (int c=0;c<CINP;c+=4){
      float wd0 = WdT[(c+0)*COUT+o], wc0 = WcdT[(c+0)*COUT+o];
      float wd1 = WdT[(c+1)*COUT+o], wc1 = WcdT[(c+1)*COUT+o];
      float wd2 = WdT[(c+2)*COUT+o], wc2 = WcdT[(c+2)*COUT+o];
      float wd3 = WdT[(c+3)*COUT+o], wc3 = WcdT[(c+3)*COUT+o];
#pragma unroll
      for (int pp=0;pp<NP;pp++){
        float4 xv = *(const float4*)&xs[(grp+pp*G)*CINP + c];
        u[pp] = fmaf(xv.x,wd0,fmaf(xv.y,wd1,fmaf(xv.z,wd2,fmaf(xv.w,wd3,u[pp]))));
        v[pp] = fmaf(xv.x,wc0,fmaf(xv.y,wc1,fmaf(xv.z,wc2,fmaf(xv.w,wc3,v[pp]))));
      }
    }
#pragma unroll
    for (int pp=0;pp<NP;pp++){
      int p = grp + pp*G;
      ut[(size_t)(base+p)*COUT + o] = u[pp];
      vt[(size_t)(base+p)*COUT + o] = v[pp];
    }
    return;
  }
  // ---------- topk
  int row_id = (blockIdx.x*256 + tid) >> 6;
  int lane = tid & 63;
  const float* row = negD + (size_t)row_id*NN;
  float v[16];
#pragma unroll
  for (int j=0;j<4;j++){
    float4 f = *(const float4*)&row[j*256 + lane*4];
    v[j*4+0]=f.x; v[j*4+1]=f.y; v[j*4+2]=f.z; v[j*4+3]=f.w;
  }
  int* orow = idx + (size_t)row_id*KK;
  for (int k=0;k<KK;k++){
    float bv = v[0]; int bs = 0;
#pragma unroll
    for (int s=1;s<16;s++){ if (v[s] > bv){ bv = v[s]; bs = s; } }
    int bidx = (bs>>2)*256 + lane*4 + (bs&3);
    unsigned long long key = ((unsigned long long)f2u_ord(bv) << 32) | (unsigned)(1023 - bidx);
#pragma unroll
    for (int off=32; off; off>>=1){
      unsigned long long o = __shfl_xor(key, off, 64);
      if (o > key) key = o;
    }
    int widx = 1023 - (int)(key & 0xFFFFFFFFu);
    if (lane == 0) orow[k] = widx;
    bool mine = (((widx >> 2) & 63) == lane);
    int wslot = ((widx >> 8) << 2) | (widx & 3);
#pragma unroll
    for (int s=0;s<16;s++){
      if (mine && s == wslot) v[s] = -1e30f;
    }
  }
}

// ---------------- gather: h[n,k,o] = ut[m(n,k)][o] + vt[n][o]; max/min + BN sums
template<int COUT>
__global__ __launch_bounds__(256, 4) void ebgather_kernel(
    const int* __restrict__ idx, const float* __restrict__ ut, const float* __restrict__ vt,
    float* __restrict__ hmaxb, float* __restrict__ hminb, float* __restrict__ stats){
  constexpr int CHG = COUT/64;
  __shared__ float sred[128];
  int w = threadIdx.x >> 6, lane = threadIdx.x & 63;
  int pb  = blockIdx.x / CHG;
  int chg = blockIdx.x % CHG;
  int n = pb*4 + w;
  int b = n >> 10;
  if (threadIdx.x < 128) sred[threadIdx.x] = 0.f;
  __syncthreads();
  const int* irow = idx + (size_t)n*KK;
  int m[KK];
#pragma unroll
  for (int k=0;k<KK;k++) m[k] = irow[k];
  int co = chg*64 + lane;
  float vr = vt[(size_t)n*COUT + co];
  float h[KK];
#pragma unroll
  for (int k=0;k<KK;k++)
    h[k] = ut[(size_t)(b*NN + m[k])*COUT + co] + vr;
  float hx=-1e30f, hn=1e30f, s1=0.f, s2=0.f;
#pragma unroll
  for (int k=0;k<KK;k++){
    hx = fmaxf(hx, h[k]);
    hn = fminf(hn, h[k]);
    s1 += h[k];
    s2 = fmaf(h[k], h[k], s2);
  }
  hmaxb[(size_t)n*COUT + co] = hx;
  hminb[(size_t)n*COUT + co] = hn;
  atomicAdd(&sred[lane], s1);
  atomicAdd(&sred[64+lane], s2);
  __syncthreads();
  if (threadIdx.x < 128){
    int which = threadIdx.x >> 6, l = threadIdx.x & 63;
    atomicAdd(&stats[which*COUT + chg*64 + l], sred[which*64 + l]);
  }
}

// ---------------- apply (finalize inline): out = lrelu(a*(a>=0?hmax:hmin)+c)
template<int COUT>
__global__ __launch_bounds__(256) void ebapply_kernel(
    const void* __restrict__ x,
    const float* __restrict__ hmaxb, const float* __restrict__ hminb,
    const float* __restrict__ stats, const void* __restrict__ g, const void* __restrict__ bb,
    float* __restrict__ outp, int outoff){
  const int bf = detect_bf(x);
  int t = blockIdx.x*256 + threadIdx.x;
  if (t >= BB*NN*COUT) return;
  int n = t / COUT, o = t % COUT;
  const float inv_count = 1.f/(BB*NN*KK);
  float m = stats[o]*inv_count;
  float var = stats[COUT+o]*inv_count - m*m;
  float a = ldin(g,o,bf)*rsqrtf(fmaxf(var,0.f) + EPSB);
  float c = ldin(bb,o,bf) - m*a;
  float h = (a >= 0.f) ? hmaxb[t] : hminb[t];
  outp[(size_t)n*512 + outoff + o] = lrelu(fmaf(a,h,c));
}

// ---------------- conv5 via MFMA bf16: single pass, h -> bf16 hbuf + BN stats.
__global__ __launch_bounds__(256, 3) void fc5_mfma(
    const float* __restrict__ xcat, const unsigned short* __restrict__ wb5,
    float* __restrict__ st5, unsigned short* __restrict__ hbufb){
  __shared__ unsigned As[16*256];
  int tid = threadIdx.x;
  int pblk = blockIdx.x >> 2;
  int seg  = blockIdx.x & 3;
  int n0g = pblk*16;
  for (int t = tid; t < 16*256; t += 256){
    int r = t >> 8, d = t & 255;
    float2 xv = *(const float2*)&xcat[(size_t)(n0g + r)*512 + d*2];
    unsigned pk = (unsigned)f2bf(xv.x) | ((unsigned)f2bf(xv.y) << 16);
    int gs = (d >> 2) ^ r;
    As[r*256 + (gs<<2) + (d&3)] = pk;
  }
  __syncthreads();
  int w = tid>>6, lane = tid&63, col = lane&15, quad = lane>>4;
  sbf8 afr[16];
#pragma unroll
  for (int ks=0; ks<16; ks++){
    int gs = (ks*4 + quad) ^ col;
    afr[ks] = *(const sbf8*)((const unsigned short*)As + col*512 + gs*8);
  }
#pragma unroll 1
  for (int i=0;i<4;i++){
    int obase = seg*256 + w*64 + i*16;
    const unsigned short* wrow = wb5 + (size_t)(obase+col)*512 + quad*8;
    f32x4 a0 = {0.f,0.f,0.f,0.f}, a1 = {0.f,0.f,0.f,0.f};
    f32x4 a2 = {0.f,0.f,0.f,0.f}, a3 = {0.f,0.f,0.f,0.f};
#pragma unroll
    for (int ks=0; ks<4; ks++){
      sbf8 b0 = *(const sbf8*)(wrow + (ks*4+0)*32);
      sbf8 b1 = *(const sbf8*)(wrow + (ks*4+1)*32);
      sbf8 b2 = *(const sbf8*)(wrow + (ks*4+2)*32);
      sbf8 b3 = *(const sbf8*)(wrow + (ks*4+3)*32);
      a0 = __builtin_amdgcn_mfma_f32_16x16x32_bf16(afr[ks*4+0], b0, a0, 0, 0, 0);
      a1 = __builtin_amdgcn_mfma_f32_16x16x32_bf16(afr[ks*4+1], b1, a1, 0, 0, 0);
      a2 = __builtin_amdgcn_mfma_f32_16x16x32_bf16(afr[ks*4+2], b2, a2, 0, 0, 0);
      a3 = __builtin_amdgcn_mfma_f32_16x16x32_bf16(afr[ks*4+3], b3, a3, 0, 0, 0);
    }
    f32x4 acc = (a0 + a1) + (a2 + a3);
    float s1 = acc.x+acc.y+acc.z+acc.w;
    float s2 = acc.x*acc.x + acc.y*acc.y + acc.z*acc.z + acc.w*acc.w;
    s1 += __shfl_xor(s1,16,64); s2 += __shfl_xor(s2,16,64);
    s1 += __shfl_xor(s1,32,64); s2 += __shfl_xor(s2,32,64);
    if (lane < 16){
      atomicAdd(&st5[obase+lane], s1);
      atomicAdd(&st5[1024+obase+lane], s2);
    }
    unsigned short hv[4] = {f2bf(acc.x), f2bf(acc.y), f2bf(acc.z), f2bf(acc.w)};
#pragma unroll
    for (int r=0;r<4;r++)
      hbufb[(size_t)(n0g + quad*4 + r)*1024 + obase + col] = hv[r];
  }
}

// ---------------- pool over n (finalize inline): max & mean of lrelu(a*h+c); h bf16
__global__ __launch_bounds__(256) void pool5_kernel(
    const void* __restrict__ x,
    const unsigned short* __restrict__ hbufb, const float* __restrict__ st5,
    const void* __restrict__ g5, const void* __restrict__ b5,
    unsigned* __restrict__ pmax, float* __restrict__ psum){
  const int bf = detect_bf(x);
  int b = blockIdx.x >> 5;
  int ns = blockIdx.x & 31;
  int o4 = threadIdx.x*4;
  const float inv_count = 1.f/(BB*NN);
  float a[4], c[4];
#pragma unroll
  for (int j=0;j<4;j++){
    int o = o4+j;
    float m = st5[o]*inv_count;
    float var = st5[1024+o]*inv_count - m*m;
    a[j] = ldin(g5,o,bf)*rsqrtf(fmaxf(var,0.f)+EPSB);
    c[j] = ldin(b5,o,bf) - m*a[j];
  }
  float mx0=-1e30f,mx1=-1e30f,mx2=-1e30f,mx3=-1e30f;
  float sm0=0.f,sm1=0.f,sm2=0.f,sm3=0.f;
  for (int n = ns*32; n < ns*32+32; n++){
    ushort4 hu = *(const ushort4*)&hbufb[(size_t)(b*NN + n)*1024 + o4];
    float t0 = lrelu(fmaf(a[0],bf2f(hu.x),c[0]));
    float t1 = lrelu(fmaf(a[1],bf2f(hu.y),c[1]));
    float t2 = lrelu(fmaf(a[2],bf2f(hu.z),c[2]));
    float t3 = lrelu(fmaf(a[3],bf2f(hu.w),c[3]));
    mx0=fmaxf(mx0,t0); mx1=fmaxf(mx1,t1); mx2=fmaxf(mx2,t2); mx3=fmaxf(mx3,t3);
    sm0+=t0; sm1+=t1; sm2+=t2; sm3+=t3;
  }
  atomicMax(&pmax[b*1024+o4+0], f2u_ord(mx0));
  atomicMax(&pmax[b*1024+o4+1], f2u_ord(mx1));
  atomicMax(&pmax[b*1024+o4+2], f2u_ord(mx2));
  atomicMax(&pmax[b*1024+o4+3], f2u_ord(mx3));
  atomicAdd(&psum[b*1024+o4+0], sm0);
  atomicAdd(&psum[b*1024+o4+1], sm1);
  atomicAdd(&psum[b*1024+o4+2], sm2);
  atomicAdd(&psum[b*1024+o4+3], sm3);
}

// ---------------- FC head (fc6 inlines pool_finalize from pmax/psum)
__global__ __launch_bounds__(256) void fc6_kernel(
    const void* __restrict__ x,
    const unsigned* __restrict__ pmax, const float* __restrict__ psum,
    const void* __restrict__ W,
    const void* __restrict__ g, const void* __restrict__ bb, float* __restrict__ y6){
  __shared__ float red[8][256];
  int o = blockIdx.x, tid = threadIdx.x;
  const int bf = detect_bf(x);
  float part[8];
#pragma unroll
  for (int b=0;b<8;b++) part[b]=0.f;
  for (int c=tid;c<2048;c+=256){
    float wv = ldin(W,o*2048+c,bf);
#pragma unroll
    for (int b=0;b<8;b++){
      float pv = (c < 1024) ? u2f_ord(pmax[b*1024+c])
                            : psum[b*1024 + (c-1024)] * (1.f/1024.f);
      part[b] = fmaf(pv, wv, part[b]);
    }
  }
#pragma unroll
  for (int b=0;b<8;b++) red[b][tid]=part[b];
  __syncthreads();
  for (int s=128;s;s>>=1){
    if (tid<s){
#pragma unroll
      for (int b=0;b<8;b++) red[b][tid]+=red[b][tid+s];
    }
    __syncthreads();
  }
  if (tid==0){
    float y[8], m=0.f;
#pragma unroll
    for (int b=0;b<8;b++){ y[b]=red[b][0]; m+=y[b]; }
    m *= 0.125f;
    float v=0.f;
#pragma unroll
    for (int b=0;b<8;b++){ float d=y[b]-m; v += d*d; }
    v *= 0.125f;
    float a=ldin(g,o,bf)*rsqrtf(fmaxf(v,0.f)+EPSB), c0=ldin(bb,o,bf)-m*a;
#pragma unroll
    for (int b=0;b<8;b++) y6[b*512+o]=lrelu(fmaf(a,y[b],c0));
  }
}

__global__ __launch_bounds__(256) void fc7_kernel(
    const void* __restrict__ x,
    const float* __restrict__ y6, const void* __restrict__ W, const void* __restrict__ bias,
    const void* __restrict__ g, const void* __restrict__ bb, float* __restrict__ y7){
  __shared__ float red[8][256];
  int o = blockIdx.x, tid = threadIdx.x;
  const int bf = detect_bf(x);
  float part[8];
#pragma unroll
  for (int b=0;b<8;b++) part[b]=0.f;
  for (int c=tid;c<512;c+=256){
    float wv = ldin(W,o*512+c,bf);
#pragma unroll
    for (int b=0;b<8;b++) part[b] = fmaf(y6[b*512+c], wv, part[b]);
  }
#pragma unroll
  for (int b=0;b<8;b++) red[b][tid]=part[b];
  __syncthreads();
  for (int s=128;s;s>>=1){
    if (tid<s){
#pragma unroll
      for (int b=0;b<8;b++) red[b][tid]+=red[b][tid+s];
    }
    __syncthreads();
  }
  if (tid==0){
    float bs = ldin(bias,o,bf);
    float y[8], m=0.f;
#pragma unroll
    for (int b=0;b<8;b++){ y[b]=red[b][0]+bs; m+=y[b]; }
    m *= 0.125f;
    float v=0.f;
#pragma unroll
    for (int b=0;b<8;b++){ float d=y[b]-m; v += d*d; }
    v *= 0.125f;
    float a=ldin(g,o,bf)*rsqrtf(fmaxf(v,0.f)+EPSB), c0=ldin(bb,o,bf)-m*a;
#pragma unroll
    for (int b=0;b<8;b++) y7[b*256+o]=lrelu(fmaf(a,y[b],c0));
  }
}

__global__ __launch_bounds__(256) void fc8_kernel(
    const void* __restrict__ x,
    const float* __restrict__ y7, const void* __restrict__ W, const void* __restrict__ bias,
    void* __restrict__ out){
  __shared__ float red[8][256];
  int o = blockIdx.x, tid = threadIdx.x;
  const int bf = detect_bf(x);
  float wv = ldin(W,o*256+tid,bf);
#pragma unroll
  for (int b=0;b<8;b++) red[b][tid] = y7[b*256+tid]*wv;
  __syncthreads();
  for (int s=128;s;s>>=1){
    if (tid<s){
#pragma unroll
      for (int b=0;b<8;b++) red[b][tid]+=red[b][tid+s];
    }
    __syncthreads();
  }
  if (tid==0){
    float bs = ldin(bias,o,bf);
#pragma unroll
    for (int b=0;b<8;b++){
      float r = red[b][0]+bs;
      if (bf) ((bf16*)out)[b*40+o] = __float2bfloat16(r);
      else    ((float*)out)[b*40+o] = r;
    }
  }
}

extern "C" void kernel_launch(void* const* d_in, const int* in_sizes, int n_in,
                              void* d_out, int out_size, void* d_ws, size_t ws_size,
                              hipStream_t stream){
  const void* x    = d_in[0];
  const void* w00  = d_in[1];
  const void* g00  = d_in[2];
  const void* b00  = d_in[3];
  const void* w01  = d_in[4];
  const void* g01  = d_in[5];
  const void* b01  = d_in[6];
  const void* w1   = d_in[7];  const void* g1 = d_in[8];  const void* b1 = d_in[9];
  const void* w2   = d_in[10]; const void* g2 = d_in[11]; const void* b2 = d_in[12];
  const void* w3   = d_in[13]; const void* g3 = d_in[14]; const void* b3 = d_in[15];
  const void* w4   = d_in[16]; const void* g4 = d_in[17]; const void* b4 = d_in[18];
  const void* w5   = d_in[19]; const void* g5 = d_in[20]; const void* b5 = d_in[21];
  const void* w6   = d_in[22]; const void* g6 = d_in[23]; const void* b6 = d_in[24];
  const void* w7   = d_in[25]; const void* bias7 = d_in[26];
  const void* g7   = d_in[27]; const void* b7 = d_in[28];
  const void* w8   = d_in[29]; const void* bias8 = d_in[30];

  float* ws = (float*)d_ws;
  // workspace layout (float offsets)
  size_t o_xc0  = 0;                              // B*N*16
  size_t o_xcat = o_xc0  + (size_t)BB*NN*16;      // B*N*512
  size_t o_negd = o_xcat + (size_t)BB*NN*512;     // B*N*N (hmax/hmin overlay; h5)
  size_t o_u    = o_negd + (size_t)BB*NN*NN;      // B*N*256 dedicated (no overlay!)
  size_t o_v    = o_u    + (size_t)BB*NN*256;     // B*N*256 dedicated
  size_t o_w1d  = o_v    + (size_t)BB*NN*256;     // 12*64
  size_t o_w1c  = o_w1d  + 12*64;
  size_t o_w2d  = o_w1c  + 12*64;                 // 64*64
  size_t o_w2c  = o_w2d  + 64*64;
  size_t o_w3d  = o_w2c  + 64*64;                 // 64*128
  size_t o_w3c  = o_w3d  + 64*128;
  size_t o_w4d  = o_w3c  + 64*128;                // 128*256
  size_t o_w4c  = o_w4d  + 128*256;
  size_t o_wb5  = o_w4c  + 128*256;               // 1024*512 bf16 = 262144 floats
  size_t o_st1  = o_wb5  + 262144;                // 128  (zero region starts here)
  size_t o_st2  = o_st1  + 128;                   // 128
  size_t o_st3  = o_st2  + 128;                   // 256
  size_t o_st4  = o_st3  + 256;                   // 512
  size_t o_st5  = o_st4  + 512;                   // 2048
  size_t o_pmax = o_st5  + 2048;                  // 8*1024 (uint)
  size_t o_psum = o_pmax + 8192;                  // 8*1024
  size_t o_cst  = o_psum + 8192;                  // 16 (conv0 stats; zero region ends)
  size_t o_idx  = o_cst  + 16;                    // B*N*20 ints
  size_t o_y6   = o_idx  + (size_t)BB*NN*KK;      // 8*512
  size_t o_y7   = o_y6   + 4096;                  // 8*256

  // overlays on the negD region (written only AFTER topk consumed negD):
  size_t o_hmax = o_negd;
  size_t o_hmin = o_negd + (size_t)2*BB*NN*256;
  size_t o_h5   = o_negd;                         // B*N*1024 bf16 (after eb4 apply)

  int* idxp = (int*)(ws + o_idx);
  float* negD = ws + o_negd;
  float* xc0  = ws + o_xc0;
  float* xcat = ws + o_xcat;
  float* up   = ws + o_u;
  float* vp   = ws + o_v;
  float* hxp  = ws + o_hmax;
  float* hnp  = ws + o_hmin;
  unsigned short* wb5 = (unsigned short*)(ws + o_wb5);
  unsigned short* h5b = (unsigned short*)(ws + o_h5);

  // fused prep: zero (NZERO u32 at o_st1) + weight transforms + wb5 pack
  const int PREP_TOTAL = NZERO + 768 + 4096 + 8192 + 32768 + 1024*512;
  prep_kernel<<<(PREP_TOTAL+255)/256,256,0,stream>>>(
      x, w1,w2,w3,w4,w5, (unsigned*)(ws + o_st1),
      ws+o_w1d, ws+o_w1c, ws+o_w2d, ws+o_w2c,
      ws+o_w3d, ws+o_w3c, ws+o_w4d, ws+o_w4c, wb5);

  conv0_stats_kernel<<<32,256,0,stream>>>(x, w00, w01, ws+o_cst);
  conv0_apply_kernel<<<32,256,0,stream>>>(x, w00,g00,b00, w01,g01,b01, ws+o_cst, xc0);

  dim3 kgrid(NN/128, NN/128, BB);               // 512 blocks
  const size_t KLDS16 = (2*128*16 + 256)*4;     // CR=12 (KCH=16)
  const size_t KLDS64 = (2*128*64 + 256)*4;     // CR=64/128 (KCH=64)
  const int TUVG = 2048 + 512;                  // topk blocks + uvgemm blocks

  // ---- edge block 1
  knndist_kernel<<<kgrid,256, KLDS16, stream>>>(xc0, 16, 0, 12, negD);
  topkuv_kernel<12,64><<<TUVG,256,0,stream>>>(negD, idxp, xc0, 16, 0,
      ws+o_w1d, ws+o_w1c, up, vp);
  ebgather_kernel<64><<<(BB*NN/4)*1,256,0,stream>>>(idxp, up, vp, hxp, hnp, ws+o_st1);
  ebapply_kernel<64><<<BB*NN*64/256,256,0,stream>>>(x, hxp, hnp, ws+o_st1, g1, b1, xcat, 0);

  // ---- edge block 2
  knndist_kernel<<<kgrid,256, KLDS64, stream>>>(xcat, 512, 0, 64, negD);
  topkuv_kernel<64,64><<<TUVG,256,0,stream>>>(negD, idxp, xcat, 512, 0,
      ws+o_w2d, ws+o_w2c, up, vp);
  ebgather_kernel<64><<<(BB*NN/4)*1,256,0,stream>>>(idxp, up, vp, hxp, hnp, ws+o_st2);
  ebapply_kernel<64><<<BB*NN*64/256,256,0,stream>>>(x, hxp, hnp, ws+o_st2, g2, b2, xcat, 64);

  // ---- edge block 3
  knndist_kernel<<<kgrid,256, KLDS64, stream>>>(xcat, 512, 64, 64, negD);
  topkuv_kernel<64,128><<<TUVG,256,0,stream>>>(negD, idxp, xcat, 512, 64,
      ws+o_w3d, ws+o_w3c, up, vp);
  ebgather_kernel<128><<<(BB*NN/4)*2,256,0,stream>>>(idxp, up, vp, hxp, hnp, ws+o_st3);
  ebapply_kernel<128><<<BB*NN*128/256,256,0,stream>>>(x, hxp, hnp, ws+o_st3, g3, b3, xcat, 128);

  // ---- edge block 4
  knndist_kernel<<<kgrid,256, KLDS64, stream>>>(xcat, 512, 128, 128, negD);
  topkuv_kernel<128,256><<<TUVG,256,0,stream>>>(negD, idxp, xcat, 512, 128,
      ws+o_w4d, ws+o_w4c, up, vp);
  ebgather_kernel<256><<<(BB*NN/4)*4,256,0,stream>>>(idxp, up, vp, hxp, hnp, ws+o_st4);
  ebapply_kernel<256><<<BB*NN*256/256,256,0,stream>>>(x, hxp, hnp, ws+o_st4, g4, b4, xcat, 256);

  // ---- conv5 MFMA + pool
  fc5_mfma<<<(BB*NN/16)*4,256,0,stream>>>(xcat, wb5, ws+o_st5, h5b);
  pool5_kernel<<<BB*32,256,0,stream>>>(x, h5b, ws+o_st5, g5, b5,
                                       (unsigned*)(ws+o_pmax), ws+o_psum);

  // ---- FC head (fc6 reads pmax/psum directly)
  fc6_kernel<<<512,256,0,stream>>>(x, (unsigned*)(ws+o_pmax), ws+o_psum, w6, g6, b6, ws+o_y6);
  fc7_kernel<<<256,256,0,stream>>>(x, ws+o_y6, w7, bias7, g7, b7, ws+o_y7);
  fc8_kernel<<<40,256,0,stream>>>(x, ws+o_y7, w8, bias8, d_out);
}